// Round 4
// baseline (210.565 us; speedup 1.0000x reference)
//
#include <hip/hip_runtime.h>

typedef float  f32x2  __attribute__((ext_vector_type(2)));
typedef float  f32x4  __attribute__((ext_vector_type(4)));
typedef float  f32x16 __attribute__((ext_vector_type(16)));
typedef short  s16x4  __attribute__((ext_vector_type(4)));
typedef unsigned int u32x2 __attribute__((ext_vector_type(2)));

__device__ __forceinline__ unsigned f2bf(float f) {
    unsigned u = __builtin_bit_cast(unsigned, f);
    u += 0x7FFFu + ((u >> 16) & 1u);   // RNE
    return u >> 16;
}
__device__ __forceinline__ s16x4 pack4(float a, float b, float c, float d) {
    u32x2 u;
    u[0] = f2bf(a) | (f2bf(b) << 16);
    u[1] = f2bf(c) | (f2bf(d) << 16);
    return __builtin_bit_cast(s16x4, u);
}
__device__ __forceinline__ s16x4 pack4v(f32x4 v) { return pack4(v[0], v[1], v[2], v[3]); }

// ---------------------------------------------------------------------------
// Node MLP: P = relu(relu(X W1^T + b1) W2^T + b2) Wm^T (+ bm), stored f32.
// Storage layout: P'[node*32 + 16*g + r] = acc[r] of lane (g, node%32) — i.e.
// the accumulator quads store contiguously, and the edge kernel's gather of
// [i*32+16g .. +16) yields addends in exactly its acc layout. One wave per
// 32-node tile; 4 consecutive tiles per wave (weight frags amortized).
// ---------------------------------------------------------------------------
__device__ __forceinline__ void node_body(
    const float* __restrict__ X,
    const float* __restrict__ W1, const float* __restrict__ b1,
    const float* __restrict__ W2, const float* __restrict__ b2,
    const float* __restrict__ Wm, const float* __restrict__ bm,
    float* __restrict__ outp, int N, int tile0)
{
    const int lane = threadIdx.x & 63;
    const int g = lane >> 5, m = lane & 31;
    const int ntile = (N + 31) >> 5;
    if (tile0 >= ntile) return;

    s16x4 a1[4], a2[4], am[4];
#pragma unroll
    for (int q = 0; q < 4; ++q) {
        const float* p1 = W1 + m * 32 + 8 * q + 4 * g;
        a1[q] = pack4(p1[0], p1[1], p1[2], p1[3]);
        const float* p2 = W2 + m * 32 + 8 * q + 4 * g;
        a2[q] = pack4(p2[0], p2[1], p2[2], p2[3]);
        const float* pm = Wm + m * 96 + 8 * q + 4 * g;
        am[q] = pack4(pm[0], pm[1], pm[2], pm[3]);
    }
    f32x16 f1, f2, f3;
#pragma unroll
    for (int r = 0; r < 16; ++r) {
        int ch = (r & 3) + 8 * (r >> 2) + 4 * g;
        f1[r] = b1[ch];
        f2[r] = b2[ch];
        f3[r] = bm ? bm[ch] : 0.f;
    }

#pragma unroll
    for (int k = 0; k < 4; ++k) {
        const int tile = tile0 + k;
        if (tile >= ntile) break;
        const int node0 = tile * 32 + m;
        const int node = node0 < N ? node0 : N - 1;

        s16x4 bX[4];
#pragma unroll
        for (int q = 0; q < 4; ++q) {
            f32x4 v = *reinterpret_cast<const f32x4*>(X + (size_t)node * 32 + 8 * q + 4 * g);
            bX[q] = pack4v(v);
        }
        f32x16 acc = f1;
#pragma unroll
        for (int q = 0; q < 4; ++q) acc = __builtin_amdgcn_mfma_f32_32x32x8bf16_1k(a1[q], bX[q], acc, 0, 0, 0);
        s16x4 bH[4];
#pragma unroll
        for (int q = 0; q < 4; ++q)
            bH[q] = pack4(fmaxf(acc[4*q+0], 0.f), fmaxf(acc[4*q+1], 0.f),
                          fmaxf(acc[4*q+2], 0.f), fmaxf(acc[4*q+3], 0.f));
        acc = f2;
#pragma unroll
        for (int q = 0; q < 4; ++q) acc = __builtin_amdgcn_mfma_f32_32x32x8bf16_1k(a2[q], bH[q], acc, 0, 0, 0);
#pragma unroll
        for (int q = 0; q < 4; ++q)
            bH[q] = pack4(fmaxf(acc[4*q+0], 0.f), fmaxf(acc[4*q+1], 0.f),
                          fmaxf(acc[4*q+2], 0.f), fmaxf(acc[4*q+3], 0.f));
        acc = f3;
#pragma unroll
        for (int q = 0; q < 4; ++q) acc = __builtin_amdgcn_mfma_f32_32x32x8bf16_1k(am[q], bH[q], acc, 0, 0, 0);

        if (node0 < N) {
            float* orow = outp + (size_t)node0 * 32 + 16 * g;
#pragma unroll
            for (int q = 0; q < 4; ++q) {
                f32x4 v; v[0] = acc[4*q+0]; v[1] = acc[4*q+1];
                v[2] = acc[4*q+2]; v[3] = acc[4*q+3];
                *reinterpret_cast<f32x4*>(orow + 4 * q) = v;
            }
        }
    }
}

__global__ __launch_bounds__(256) void nodes_kernel(
    const float* __restrict__ var_f, const float* __restrict__ con_f,
    const float* __restrict__ Wv1, const float* __restrict__ bv1,
    const float* __restrict__ Wv2, const float* __restrict__ bv2,
    const float* __restrict__ Wc1, const float* __restrict__ bc1,
    const float* __restrict__ Wc2, const float* __restrict__ bc2,
    const float* __restrict__ We1, const float* __restrict__ be1,
    float* __restrict__ pv, float* __restrict__ pc,
    int nV, int nC, int wavesV)
{
    const int wvg = (blockIdx.x * blockDim.x + threadIdx.x) >> 6;
    if (wvg < wavesV) {
        node_body(var_f, Wv1, bv1, Wv2, bv2, We1 + 32, be1, pv, nV, wvg * 4);
    } else {
        node_body(con_f, Wc1, bc1, Wc2, bc2, We1 + 64, nullptr, pc, nC,
                  (wvg - wavesV) * 4);
    }
}

// ---------------------------------------------------------------------------
// Edge kernel: wave-independent, no barriers, one 32-edge tile per iteration.
// f32 gathers add DIRECTLY into the layer-1 accumulator (no identity MFMAs).
// Issue order Ef -> gathers -> next idx matches use order, so counted vmcnt
// keeps gathers + idx in flight across the Ef wait.
// ---------------------------------------------------------------------------
__global__ __launch_bounds__(256, 6) void edge_kernel(
    const float* __restrict__ Ef, const int* __restrict__ idx,
    const float* __restrict__ pv, const float* __restrict__ pc,
    const float* __restrict__ We1, const float* __restrict__ We2,
    const float* __restrict__ be2,
    float* __restrict__ out, int nE)
{
    __shared__ float ldso[4 * 1088];          // 4 waves * 32 rows * stride 34
    const int lane = threadIdx.x & 63;
    const int wv = threadIdx.x >> 6;
    const int g = lane >> 5, n = lane & 31;
    float* ldsw = ldso + wv * 1088;

    // A fragments. Layer 1: ch1(q,g,j)=16g+4q+j; layer 2: ch2=8q+4g+j.
    s16x4 aW1[4], aW2[4];
#pragma unroll
    for (int q = 0; q < 4; ++q) {
        const float* p = We1 + n * 96 + 16 * g + 4 * q;
        aW1[q] = pack4(p[0], p[1], p[2], p[3]);
        const float* p2 = We2 + n * 32 + 8 * q + 4 * g;
        aW2[q] = pack4(p2[0], p2[1], p2[2], p2[3]);
    }
    // be2 as one extra MFMA: A[:,0]=be2, B[0,:]=1
    s16x4 aB2 = {}, bOne = {};
    if (g == 0) {
        aB2[0] = (short)f2bf(be2[n]);
        bOne[0] = (short)0x3F80;
    }

    const int ntile = nE >> 5;
    const int nw = (gridDim.x * blockDim.x) >> 6;
    int t = (blockIdx.x * blockDim.x + threadIdx.x) >> 6;
    if (t >= ntile) return;

    int e0 = t * 32 + n;
    int i0 = idx[e0], i1 = idx[nE + e0];

    while (true) {
        const int tn = t + nw;

        // ---- issue: Ef(t) ----
        const float* efp = Ef + (size_t)(t * 32 + n) * 32 + 16 * g;
        f32x4 ef0 = *reinterpret_cast<const f32x4*>(efp + 0);
        f32x4 ef1 = *reinterpret_cast<const f32x4*>(efp + 4);
        f32x4 ef2 = *reinterpret_cast<const f32x4*>(efp + 8);
        f32x4 ef3 = *reinterpret_cast<const f32x4*>(efp + 12);
        // ---- issue: gathers(t), f32 addends in acc layout ----
        const float* pvr = pv + (size_t)i0 * 32 + 16 * g;
        const float* pcr = pc + (size_t)i1 * 32 + 16 * g;
        f32x4 gv0 = *reinterpret_cast<const f32x4*>(pvr + 0);
        f32x4 gv1 = *reinterpret_cast<const f32x4*>(pvr + 4);
        f32x4 gv2 = *reinterpret_cast<const f32x4*>(pvr + 8);
        f32x4 gv3 = *reinterpret_cast<const f32x4*>(pvr + 12);
        f32x4 gc0 = *reinterpret_cast<const f32x4*>(pcr + 0);
        f32x4 gc1 = *reinterpret_cast<const f32x4*>(pcr + 4);
        f32x4 gc2 = *reinterpret_cast<const f32x4*>(pcr + 8);
        f32x4 gc3 = *reinterpret_cast<const f32x4*>(pcr + 12);
        // ---- issue: idx(t+1) ----
        const int tc = tn < ntile ? tn : t;
        const int en = tc * 32 + n;
        const int i0n = idx[en];
        const int i1n = idx[nE + en];

        // ---- layer 1: Ef MFMAs ----
        f32x16 acc = {};
        {
            s16x4 bE0 = pack4v(ef0), bE1 = pack4v(ef1), bE2 = pack4v(ef2), bE3 = pack4v(ef3);
            acc = __builtin_amdgcn_mfma_f32_32x32x8bf16_1k(aW1[0], bE0, acc, 0, 0, 0);
            acc = __builtin_amdgcn_mfma_f32_32x32x8bf16_1k(aW1[1], bE1, acc, 0, 0, 0);
            acc = __builtin_amdgcn_mfma_f32_32x32x8bf16_1k(aW1[2], bE2, acc, 0, 0, 0);
            acc = __builtin_amdgcn_mfma_f32_32x32x8bf16_1k(aW1[3], bE3, acc, 0, 0, 0);
        }
        // ---- layer 1: gathered node partials (direct f32 adds) ----
        {
            f32x4 s0 = gv0 + gc0, s1 = gv1 + gc1, s2 = gv2 + gc2, s3 = gv3 + gc3;
            acc[0]  += s0[0]; acc[1]  += s0[1]; acc[2]  += s0[2]; acc[3]  += s0[3];
            acc[4]  += s1[0]; acc[5]  += s1[1]; acc[6]  += s1[2]; acc[7]  += s1[3];
            acc[8]  += s2[0]; acc[9]  += s2[1]; acc[10] += s2[2]; acc[11] += s2[3];
            acc[12] += s3[0]; acc[13] += s3[1]; acc[14] += s3[2]; acc[15] += s3[3];
        }

        // relu + pack -> layer-2 B frags (D quads align with k-groups)
        s16x4 bH[4];
#pragma unroll
        for (int q = 0; q < 4; ++q)
            bH[q] = pack4(fmaxf(acc[4*q+0], 0.f), fmaxf(acc[4*q+1], 0.f),
                          fmaxf(acc[4*q+2], 0.f), fmaxf(acc[4*q+3], 0.f));

        f32x16 acc2 = {};
        acc2 = __builtin_amdgcn_mfma_f32_32x32x8bf16_1k(aB2, bOne, acc2, 0, 0, 0);
#pragma unroll
        for (int q = 0; q < 4; ++q)
            acc2 = __builtin_amdgcn_mfma_f32_32x32x8bf16_1k(aW2[q], bH[q], acc2, 0, 0, 0);

        // ---- store: wave-private LDS transpose (stride 34), then nt stores ----
        {
            float* orow = ldsw + n * 34;
#pragma unroll
            for (int q = 0; q < 4; ++q) {
                f32x2 lo; lo[0] = acc2[4*q+0]; lo[1] = acc2[4*q+1];
                f32x2 hi; hi[0] = acc2[4*q+2]; hi[1] = acc2[4*q+3];
                *reinterpret_cast<f32x2*>(orow + 8 * q + 4 * g)     = lo;
                *reinterpret_cast<f32x2*>(orow + 8 * q + 4 * g + 2) = hi;
            }
            float* obase = out + (size_t)t * 1024;
#pragma unroll
            for (int p = 0; p < 4; ++p) {
                int li = p * 256 + lane * 4;
                int row = li >> 5, col = li & 31;
                const float* s = ldsw + row * 34 + col;
                f32x2 lo = *reinterpret_cast<const f32x2*>(s);
                f32x2 hi = *reinterpret_cast<const f32x2*>(s + 2);
                f32x4 v; v[0] = lo[0]; v[1] = lo[1]; v[2] = hi[0]; v[3] = hi[1];
                __builtin_nontemporal_store(v, reinterpret_cast<f32x4*>(obase + li));
            }
        }

        if (tn >= ntile) break;
        t = tn; i0 = i0n; i1 = i1n;
    }
}

extern "C" void kernel_launch(void* const* d_in, const int* in_sizes, int n_in,
                              void* d_out, int out_size, void* d_ws, size_t ws_size,
                              hipStream_t stream) {
    const float* var_f = (const float*)d_in[0];
    const float* con_f = (const float*)d_in[1];
    const float* Ef    = (const float*)d_in[2];
    const int*   idx   = (const int*)d_in[3];
    const float* Wv1 = (const float*)d_in[4];
    const float* bv1 = (const float*)d_in[5];
    const float* Wv2 = (const float*)d_in[6];
    const float* bv2 = (const float*)d_in[7];
    const float* Wc1 = (const float*)d_in[8];
    const float* bc1 = (const float*)d_in[9];
    const float* Wc2 = (const float*)d_in[10];
    const float* bc2 = (const float*)d_in[11];
    const float* We1 = (const float*)d_in[12];
    const float* be1 = (const float*)d_in[13];
    const float* We2 = (const float*)d_in[14];
    const float* be2 = (const float*)d_in[15];
    float* out = (float*)d_out;

    const int nV = in_sizes[0] / 32;
    const int nC = in_sizes[1] / 32;
    const int nE = in_sizes[2] / 32;

    float* pv = (float*)d_ws;
    float* pc = pv + (size_t)nV * 32;

    const int wavesV = (((nV + 31) >> 5) + 3) >> 2;
    const int wavesC = (((nC + 31) >> 5) + 3) >> 2;
    const int nodeBlocks = (wavesV + wavesC + 3) / 4;
    nodes_kernel<<<nodeBlocks, 256, 0, stream>>>(
        var_f, con_f, Wv1, bv1, Wv2, bv2, Wc1, bc1, Wc2, bc2,
        We1, be1, pv, pc, nV, nC, wavesV);

    edge_kernel<<<1536, 256, 0, stream>>>(Ef, idx, pv, pc, We1, We2, be2, out, nE);
}

// Round 5
// 169.915 us; speedup vs baseline: 1.2392x; 1.2392x over previous
//
#include <hip/hip_runtime.h>

typedef float  f32x2  __attribute__((ext_vector_type(2)));
typedef float  f32x4  __attribute__((ext_vector_type(4)));
typedef float  f32x16 __attribute__((ext_vector_type(16)));
typedef short  s16x4  __attribute__((ext_vector_type(4)));
typedef short  s16x8  __attribute__((ext_vector_type(8)));
typedef unsigned int u32x2 __attribute__((ext_vector_type(2)));

__device__ __forceinline__ unsigned f2bf(float f) {
    unsigned u = __builtin_bit_cast(unsigned, f);
    u += 0x7FFFu + ((u >> 16) & 1u);   // RNE
    return u >> 16;
}
__device__ __forceinline__ s16x4 pack4(float a, float b, float c, float d) {
    u32x2 u;
    u[0] = f2bf(a) | (f2bf(b) << 16);
    u[1] = f2bf(c) | (f2bf(d) << 16);
    return __builtin_bit_cast(s16x4, u);
}
__device__ __forceinline__ s16x4 pack4v(f32x4 v) { return pack4(v[0], v[1], v[2], v[3]); }
__device__ __forceinline__ s16x4 lo4(s16x8 v) { return __builtin_shufflevector(v, v, 0, 1, 2, 3); }
__device__ __forceinline__ s16x4 hi4(s16x8 v) { return __builtin_shufflevector(v, v, 4, 5, 6, 7); }

// ---------------------------------------------------------------------------
// Node MLP: P = relu(relu(X W1^T + b1) W2^T + b2) Wm^T (+ bm), bf16 out,
// standard channel layout P[node*32 + ch]. One wave per 32-node tile,
// 4 consecutive tiles per wave (weight-fragment setup amortized).
// ---------------------------------------------------------------------------
__device__ __forceinline__ void node_body(
    const float* __restrict__ X,
    const float* __restrict__ W1, const float* __restrict__ b1,
    const float* __restrict__ W2, const float* __restrict__ b2,
    const float* __restrict__ Wm, const float* __restrict__ bm,
    unsigned short* __restrict__ outp, int N, int tile0)
{
    const int lane = threadIdx.x & 63;
    const int g = lane >> 5, m = lane & 31;
    const int ntile = (N + 31) >> 5;
    if (tile0 >= ntile) return;

    s16x4 a1[4], a2[4], am[4];
#pragma unroll
    for (int q = 0; q < 4; ++q) {
        const float* p1 = W1 + m * 32 + 8 * q + 4 * g;
        a1[q] = pack4(p1[0], p1[1], p1[2], p1[3]);
        const float* p2 = W2 + m * 32 + 8 * q + 4 * g;
        a2[q] = pack4(p2[0], p2[1], p2[2], p2[3]);
        const float* pm = Wm + m * 96 + 8 * q + 4 * g;
        am[q] = pack4(pm[0], pm[1], pm[2], pm[3]);
    }
    f32x16 f1, f2, f3;
#pragma unroll
    for (int r = 0; r < 16; ++r) {
        int ch = (r & 3) + 8 * (r >> 2) + 4 * g;
        f1[r] = b1[ch];
        f2[r] = b2[ch];
        f3[r] = bm ? bm[ch] : 0.f;
    }

#pragma unroll
    for (int k = 0; k < 4; ++k) {
        const int tile = tile0 + k;
        if (tile >= ntile) break;
        const int node0 = tile * 32 + m;
        const int node = node0 < N ? node0 : N - 1;

        s16x4 bX[4];
#pragma unroll
        for (int q = 0; q < 4; ++q) {
            f32x4 v = *reinterpret_cast<const f32x4*>(X + (size_t)node * 32 + 8 * q + 4 * g);
            bX[q] = pack4v(v);
        }
        f32x16 acc = f1;
#pragma unroll
        for (int q = 0; q < 4; ++q) acc = __builtin_amdgcn_mfma_f32_32x32x8bf16_1k(a1[q], bX[q], acc, 0, 0, 0);
        s16x4 bH[4];
#pragma unroll
        for (int q = 0; q < 4; ++q)
            bH[q] = pack4(fmaxf(acc[4*q+0], 0.f), fmaxf(acc[4*q+1], 0.f),
                          fmaxf(acc[4*q+2], 0.f), fmaxf(acc[4*q+3], 0.f));
        acc = f2;
#pragma unroll
        for (int q = 0; q < 4; ++q) acc = __builtin_amdgcn_mfma_f32_32x32x8bf16_1k(a2[q], bH[q], acc, 0, 0, 0);
#pragma unroll
        for (int q = 0; q < 4; ++q)
            bH[q] = pack4(fmaxf(acc[4*q+0], 0.f), fmaxf(acc[4*q+1], 0.f),
                          fmaxf(acc[4*q+2], 0.f), fmaxf(acc[4*q+3], 0.f));
        acc = f3;
#pragma unroll
        for (int q = 0; q < 4; ++q) acc = __builtin_amdgcn_mfma_f32_32x32x8bf16_1k(am[q], bH[q], acc, 0, 0, 0);

        if (node0 < N) {
#pragma unroll
            for (int q = 0; q < 4; ++q) {
                s16x4 o = pack4(acc[4*q+0], acc[4*q+1], acc[4*q+2], acc[4*q+3]);
                *reinterpret_cast<s16x4*>(outp + (size_t)node0 * 32 + 8 * q + 4 * g) = o;
            }
        }
    }
}

__global__ __launch_bounds__(256) void nodes_kernel(
    const float* __restrict__ var_f, const float* __restrict__ con_f,
    const float* __restrict__ Wv1, const float* __restrict__ bv1,
    const float* __restrict__ Wv2, const float* __restrict__ bv2,
    const float* __restrict__ Wc1, const float* __restrict__ bc1,
    const float* __restrict__ Wc2, const float* __restrict__ bc2,
    const float* __restrict__ We1, const float* __restrict__ be1,
    unsigned short* __restrict__ pv, unsigned short* __restrict__ pc,
    int nV, int nC, int wavesV)
{
    const int wvg = (blockIdx.x * blockDim.x + threadIdx.x) >> 6;
    if (wvg < wavesV) {
        node_body(var_f, Wv1, bv1, Wv2, bv2, We1 + 32, be1, pv, nV, wvg * 4);
    } else {
        node_body(con_f, Wc1, bc1, Wc2, bc2, We1 + 64, nullptr, pc, nC,
                  (wvg - wavesV) * 4);
    }
}

// ---------------------------------------------------------------------------
// Edge kernel: wave-independent, no barriers. FULL depth-1 software pipeline:
// at the top of iteration t we issue Ef(t+1), gathers(t+1) (idx fetched two
// ahead), idx(t+2); the compute of tile t uses registers loaded one full
// iteration ago, so every VMEM load has an entire iteration of issue distance.
// bf16 node partials consumed via identity MFMAs (ch1 = 16g+4q+j mapping);
// layer-2 uses ch2 = 8q+4g+j so D->B chains in-register.
// ---------------------------------------------------------------------------
__global__ __launch_bounds__(256, 4) void edge_kernel(
    const float* __restrict__ Ef, const int* __restrict__ idx,
    const unsigned short* __restrict__ pv, const unsigned short* __restrict__ pc,
    const float* __restrict__ We1, const float* __restrict__ We2,
    const float* __restrict__ be2,
    float* __restrict__ out, int nE)
{
    __shared__ float ldso[4 * 1088];          // 4 waves * 32 rows * stride 34
    const int lane = threadIdx.x & 63;
    const int wv = threadIdx.x >> 6;
    const int g = lane >> 5, n = lane & 31;
    float* ldsw = ldso + wv * 1088;

    // A fragments. Layer 1: ch1(q,g,j)=16g+4q+j; layer 2: ch2=8q+4g+j.
    s16x4 aW1[4], aI[4], aW2[4];
#pragma unroll
    for (int q = 0; q < 4; ++q) {
        const float* p = We1 + n * 96 + 16 * g + 4 * q;
        aW1[q] = pack4(p[0], p[1], p[2], p[3]);
        s16x4 r;
#pragma unroll
        for (int j = 0; j < 4; ++j) r[j] = (short)((16 * g + 4 * q + j == n) ? 0x3F80 : 0);
        aI[q] = r;
        const float* p2 = We2 + n * 32 + 8 * q + 4 * g;
        aW2[q] = pack4(p2[0], p2[1], p2[2], p2[3]);
    }
    // be2 as one extra MFMA: A[:,0]=be2, B[0,:]=1
    s16x4 aB2 = {}, bOne = {};
    if (g == 0) {
        aB2[0] = (short)f2bf(be2[n]);
        bOne[0] = (short)0x3F80;
    }

    const int ntile = nE >> 5;
    const int nw = (gridDim.x * blockDim.x) >> 6;
    int t = (blockIdx.x * blockDim.x + threadIdx.x) >> 6;
    if (t >= ntile) return;

    // ---- prologue: fill stage for tile t, plus idx for t+nw ----
    int e0 = t * 32 + n;
    int ia0 = idx[e0], ia1 = idx[nE + e0];
    const float* efp = Ef + (size_t)e0 * 32 + 16 * g;
    f32x4 ce0 = *reinterpret_cast<const f32x4*>(efp + 0);
    f32x4 ce1 = *reinterpret_cast<const f32x4*>(efp + 4);
    f32x4 ce2 = *reinterpret_cast<const f32x4*>(efp + 8);
    f32x4 ce3 = *reinterpret_cast<const f32x4*>(efp + 12);
    const unsigned short* pvr0 = pv + (size_t)ia0 * 32 + 16 * g;
    const unsigned short* pcr0 = pc + (size_t)ia1 * 32 + 16 * g;
    s16x8 cv0 = *reinterpret_cast<const s16x8*>(pvr0);
    s16x8 cv1 = *reinterpret_cast<const s16x8*>(pvr0 + 8);
    s16x8 cc0 = *reinterpret_cast<const s16x8*>(pcr0);
    s16x8 cc1 = *reinterpret_cast<const s16x8*>(pcr0 + 8);
    {
        int t1 = (t + nw < ntile) ? t + nw : t;
        int e1 = t1 * 32 + n;
        // idx for the NEXT tile (consumed next iteration's prefetch)
        ia0 = idx[e1]; ia1 = idx[nE + e1];   // reuse ia as "idx of t+nw"
    }
    int ib0 = ia0, ib1 = ia1;

    while (true) {
        const int tn = t + nw;
        const int tc = tn < ntile ? tn : t;

        // ---- issue stage(t+nw): Ef ----
        const float* efpn = Ef + (size_t)(tc * 32 + n) * 32 + 16 * g;
        f32x4 ne0 = *reinterpret_cast<const f32x4*>(efpn + 0);
        f32x4 ne1 = *reinterpret_cast<const f32x4*>(efpn + 4);
        f32x4 ne2 = *reinterpret_cast<const f32x4*>(efpn + 8);
        f32x4 ne3 = *reinterpret_cast<const f32x4*>(efpn + 12);
        // ---- issue stage(t+nw): gathers (idx already resident) ----
        const unsigned short* pvn = pv + (size_t)ib0 * 32 + 16 * g;
        const unsigned short* pcn = pc + (size_t)ib1 * 32 + 16 * g;
        s16x8 nv0 = *reinterpret_cast<const s16x8*>(pvn);
        s16x8 nv1 = *reinterpret_cast<const s16x8*>(pvn + 8);
        s16x8 nc0 = *reinterpret_cast<const s16x8*>(pcn);
        s16x8 nc1 = *reinterpret_cast<const s16x8*>(pcn + 8);
        // ---- issue idx(t+2*nw) ----
        int t2 = (tn + nw < ntile) ? tn + nw : tc;
        int e2 = t2 * 32 + n;
        int ic0 = idx[e2], ic1 = idx[nE + e2];

        // ---- compute tile t from current-stage registers ----
        f32x16 acc = {};
        {
            s16x4 bE0 = pack4v(ce0), bE1 = pack4v(ce1), bE2 = pack4v(ce2), bE3 = pack4v(ce3);
            acc = __builtin_amdgcn_mfma_f32_32x32x8bf16_1k(aW1[0], bE0, acc, 0, 0, 0);
            acc = __builtin_amdgcn_mfma_f32_32x32x8bf16_1k(aW1[1], bE1, acc, 0, 0, 0);
            acc = __builtin_amdgcn_mfma_f32_32x32x8bf16_1k(aW1[2], bE2, acc, 0, 0, 0);
            acc = __builtin_amdgcn_mfma_f32_32x32x8bf16_1k(aW1[3], bE3, acc, 0, 0, 0);
        }
        acc = __builtin_amdgcn_mfma_f32_32x32x8bf16_1k(aI[0], lo4(cv0), acc, 0, 0, 0);
        acc = __builtin_amdgcn_mfma_f32_32x32x8bf16_1k(aI[1], hi4(cv0), acc, 0, 0, 0);
        acc = __builtin_amdgcn_mfma_f32_32x32x8bf16_1k(aI[2], lo4(cv1), acc, 0, 0, 0);
        acc = __builtin_amdgcn_mfma_f32_32x32x8bf16_1k(aI[3], hi4(cv1), acc, 0, 0, 0);
        acc = __builtin_amdgcn_mfma_f32_32x32x8bf16_1k(aI[0], lo4(cc0), acc, 0, 0, 0);
        acc = __builtin_amdgcn_mfma_f32_32x32x8bf16_1k(aI[1], hi4(cc0), acc, 0, 0, 0);
        acc = __builtin_amdgcn_mfma_f32_32x32x8bf16_1k(aI[2], lo4(cc1), acc, 0, 0, 0);
        acc = __builtin_amdgcn_mfma_f32_32x32x8bf16_1k(aI[3], hi4(cc1), acc, 0, 0, 0);

        s16x4 bH[4];
#pragma unroll
        for (int q = 0; q < 4; ++q)
            bH[q] = pack4(fmaxf(acc[4*q+0], 0.f), fmaxf(acc[4*q+1], 0.f),
                          fmaxf(acc[4*q+2], 0.f), fmaxf(acc[4*q+3], 0.f));

        f32x16 acc2 = {};
        acc2 = __builtin_amdgcn_mfma_f32_32x32x8bf16_1k(aB2, bOne, acc2, 0, 0, 0);
#pragma unroll
        for (int q = 0; q < 4; ++q)
            acc2 = __builtin_amdgcn_mfma_f32_32x32x8bf16_1k(aW2[q], bH[q], acc2, 0, 0, 0);

        // ---- store: wave-private LDS transpose (stride 34), then NT stores ----
        {
            float* orow = ldsw + n * 34;
#pragma unroll
            for (int q = 0; q < 4; ++q) {
                f32x2 lo; lo[0] = acc2[4*q+0]; lo[1] = acc2[4*q+1];
                f32x2 hi; hi[0] = acc2[4*q+2]; hi[1] = acc2[4*q+3];
                *reinterpret_cast<f32x2*>(orow + 8 * q + 4 * g)     = lo;
                *reinterpret_cast<f32x2*>(orow + 8 * q + 4 * g + 2) = hi;
            }
            float* obase = out + (size_t)t * 1024;
#pragma unroll
            for (int p = 0; p < 4; ++p) {
                int li = p * 256 + lane * 4;
                int row = li >> 5, col = li & 31;
                const float* s = ldsw + row * 34 + col;
                f32x2 lo = *reinterpret_cast<const f32x2*>(s);
                f32x2 hi = *reinterpret_cast<const f32x2*>(s + 2);
                f32x4 v; v[0] = lo[0]; v[1] = lo[1]; v[2] = hi[0]; v[3] = hi[1];
                __builtin_nontemporal_store(v, reinterpret_cast<f32x4*>(obase + li));
            }
        }

        if (tn >= ntile) break;
        t = tn;
        ce0 = ne0; ce1 = ne1; ce2 = ne2; ce3 = ne3;
        cv0 = nv0; cv1 = nv1; cc0 = nc0; cc1 = nc1;
        ib0 = ic0; ib1 = ic1;
    }
}

extern "C" void kernel_launch(void* const* d_in, const int* in_sizes, int n_in,
                              void* d_out, int out_size, void* d_ws, size_t ws_size,
                              hipStream_t stream) {
    const float* var_f = (const float*)d_in[0];
    const float* con_f = (const float*)d_in[1];
    const float* Ef    = (const float*)d_in[2];
    const int*   idx   = (const int*)d_in[3];
    const float* Wv1 = (const float*)d_in[4];
    const float* bv1 = (const float*)d_in[5];
    const float* Wv2 = (const float*)d_in[6];
    const float* bv2 = (const float*)d_in[7];
    const float* Wc1 = (const float*)d_in[8];
    const float* bc1 = (const float*)d_in[9];
    const float* Wc2 = (const float*)d_in[10];
    const float* bc2 = (const float*)d_in[11];
    const float* We1 = (const float*)d_in[12];
    const float* be1 = (const float*)d_in[13];
    const float* We2 = (const float*)d_in[14];
    const float* be2 = (const float*)d_in[15];
    float* out = (float*)d_out;

    const int nV = in_sizes[0] / 32;
    const int nC = in_sizes[1] / 32;
    const int nE = in_sizes[2] / 32;

    unsigned short* pv = (unsigned short*)d_ws;
    unsigned short* pc = pv + (size_t)nV * 32;

    const int wavesV = (((nV + 31) >> 5) + 3) >> 2;
    const int wavesC = (((nC + 31) >> 5) + 3) >> 2;
    const int nodeBlocks = (wavesV + wavesC + 3) / 4;
    nodes_kernel<<<nodeBlocks, 256, 0, stream>>>(
        var_f, con_f, Wv1, bv1, Wv2, bv2, Wc1, bc1, Wc2, bc2,
        We1, be1, pv, pc, nV, nC, wavesV);

    edge_kernel<<<1024, 256, 0, stream>>>(Ef, idx, pv, pc, We1, We2, be2, out, nE);
}